// Round 13
// baseline (73.067 us; speedup 1.0000x reference)
//
#include <hip/hip_runtime.h>
#include <hip/hip_bf16.h>
#include <math.h>

#define MARGIN_F 6.0f
// phase = pr / (REL_RANGE/PI) = pr * (PI / 0.03125)
#define PHASE_SCALE 100.53096491487338f

// ---------------------------------------------------------------------------
// K1: fused prep. grid = 16 blocks (one per b), 1024 threads (16 waves).
// rot layout in ws: rot_re[16][256] at float offset 0, rot_im at 4096.
// ---------------------------------------------------------------------------
__global__ void k_prep(const float* __restrict__ qh, const float* __restrict__ W,
                       const float* __restrict__ brel,
                       const float* __restrict__ rel,
                       const float* __restrict__ ent, const int* __restrict__ hid,
                       float* __restrict__ rot) {
    __shared__ float q[768];
    __shared__ float sig[18];
    int b = blockIdx.x;
    int t = threadIdx.x;

    if (t < 768) {
        float s = 0.f;
        const float* base = qh + (size_t)b * 64 * 768 + t;
        #pragma unroll 8
        for (int srow = 0; srow < 64; ++srow) s += base[(size_t)srow * 768];
        q[t] = s * (1.0f / 64.0f);
    }
    __syncthreads();

    int wave = t >> 6, lane = t & 63;
    for (int r = wave; r < 18; r += 16) {
        float p = 0.f;
        for (int h = lane; h < 768; h += 64) p += q[h] * W[r * 768 + h];
        for (int off = 32; off; off >>= 1) p += __shfl_xor(p, off, 64);
        if (lane == 0) sig[r] = 1.0f / (1.0f + expf(-(p + brel[r])));
    }
    __syncthreads();

    if (t < 256) {
        int d = t;
        float pr = 0.f;
        #pragma unroll
        for (int r = 0; r < 18; ++r) pr += sig[r] * rel[r * 256 + d];
        float phase = pr * PHASE_SCALE;
        float sn, cs;
        sincosf(phase, &sn, &cs);
        int h0 = hid[b];
        float reh = ent[(size_t)h0 * 512 + d];
        float imh = ent[(size_t)h0 * 512 + 256 + d];
        rot[b * 256 + d]        = reh * cs - imh * sn;  // rot_re
        rot[4096 + b * 256 + d] = reh * sn + imh * cs;  // rot_im
    }
}

// ---------------------------------------------------------------------------
// K2: r10 compute core (4 waves/block, wave w owns b=4w..4w+3, pinned rot,
// G=2 interleaved compaction reduce) + LDS entity staging:
//  - 8 entity rows (16 KB) staged ONCE per phase -> 4x less global traffic
//    and te/ti served from LDS (~30cyc, conflict-free stride-16B b128)
//  - T14 async split: next phase's 4 global loads issue BEFORE compute,
//    LDS write after the barrier -> HBM/L3 latency hidden under ~2700cyc math
// Cross-round invariant: all shapes execute ~34-37us of VALU-busy; this
// round attacks the 32% idle (exposed load latency + 4x L1 redundancy).
// ---------------------------------------------------------------------------
#define PH 8  // entities per staging phase

__global__ __launch_bounds__(256, 4) void k_dist(const float* __restrict__ ent,
                                                 const float* __restrict__ rot,
                                                 float* __restrict__ out, int E,
                                                 int chunk) {
    __shared__ float4 buf[PH * 128];  // 8 rows x 512 floats = 16 KB

    int t = threadIdx.x;
    int lane = t & 63;
    int w4 = t >> 6;  // which 4 b's this wave owns

    const float4* rre4 = (const float4*)rot + (size_t)w4 * 4 * 64;
    const float4* rim4 = (const float4*)(rot + 4096) + (size_t)w4 * 4 * 64;
    float4 ra[4], ia[4];
    #pragma unroll
    for (int b = 0; b < 4; ++b) {
        ra[b] = rre4[b * 64 + lane];
        ia[b] = rim4[b * 64 + lane];
    }
    // Pin rot fragments in VGPRs (proven in r10: prevents L1 re-reads).
    #pragma unroll
    for (int b = 0; b < 4; ++b) {
        asm volatile("" : "+v"(ra[b].x), "+v"(ra[b].y), "+v"(ra[b].z), "+v"(ra[b].w));
        asm volatile("" : "+v"(ia[b].x), "+v"(ia[b].y), "+v"(ia[b].z), "+v"(ia[b].w));
    }

    // b owned by lane l (<4) after compaction: b = 2*l0 + l1 (r8/r10 mapping)
    int bout = w4 * 4 + (((lane & 1) << 1) | ((lane >> 1) & 1));

    int e0 = blockIdx.x * chunk;
    if (e0 >= E) return;  // uniform per block
    int e1 = min(e0 + chunk, E);
    int nph = (e1 - e0 + PH - 1) / PH;

    float4 sr[4];
    // prologue: stage phase 0 (rows clamped to E-1; stores guarded later)
    #pragma unroll
    for (int p = 0; p < 4; ++p) {
        int slot = p * 256 + t;
        int row = slot >> 7, j = slot & 127;
        int er = min(e0 + row, E - 1);
        sr[p] = ((const float4*)(ent + (size_t)er * 512))[j];
    }
    #pragma unroll
    for (int p = 0; p < 4; ++p) buf[p * 256 + t] = sr[p];
    __syncthreads();

    for (int ph = 0; ph < nph; ++ph) {
        int ebase = e0 + ph * PH;
        bool more = (ph + 1) < nph;
        if (more) {  // T14: issue next phase's loads before compute
            int nbase = ebase + PH;
            #pragma unroll
            for (int p = 0; p < 4; ++p) {
                int slot = p * 256 + t;
                int row = slot >> 7, j = slot & 127;
                int er = min(nbase + row, E - 1);
                sr[p] = ((const float4*)(ent + (size_t)er * 512))[j];
            }
        }

        #pragma unroll
        for (int g = 0; g < PH; g += 2) {
            float4 tea = buf[g * 128 + lane];
            float4 tia = buf[g * 128 + 64 + lane];
            float4 teb = buf[(g + 1) * 128 + lane];
            float4 tib = buf[(g + 1) * 128 + 64 + lane];

            float va[4], vb[4];
            #pragma unroll
            for (int b = 0; b < 4; ++b) {
                float dx0 = ra[b].x - tea.x, dy0 = ia[b].x - tia.x;
                float dx1 = ra[b].y - tea.y, dy1 = ia[b].y - tia.y;
                float dx2 = ra[b].z - tea.z, dy2 = ia[b].z - tia.z;
                float dx3 = ra[b].w - tea.w, dy3 = ia[b].w - tia.w;
                float s0 = __builtin_amdgcn_sqrtf(dx0 * dx0 + dy0 * dy0);
                float s1 = __builtin_amdgcn_sqrtf(dx1 * dx1 + dy1 * dy1);
                float s2 = __builtin_amdgcn_sqrtf(dx2 * dx2 + dy2 * dy2);
                float s3 = __builtin_amdgcn_sqrtf(dx3 * dx3 + dy3 * dy3);
                va[b] = (s0 + s1) + (s2 + s3);

                float ex0 = ra[b].x - teb.x, ey0 = ia[b].x - tib.x;
                float ex1 = ra[b].y - teb.y, ey1 = ia[b].y - tib.y;
                float ex2 = ra[b].z - teb.z, ey2 = ia[b].z - tib.z;
                float ex3 = ra[b].w - teb.w, ey3 = ia[b].w - tib.w;
                float u0 = __builtin_amdgcn_sqrtf(ex0 * ex0 + ey0 * ey0);
                float u1 = __builtin_amdgcn_sqrtf(ex1 * ex1 + ey1 * ey1);
                float u2 = __builtin_amdgcn_sqrtf(ex2 * ex2 + ey2 * ey2);
                float u3 = __builtin_amdgcn_sqrtf(ex3 * ex3 + ey3 * ey3);
                vb[b] = (u0 + u1) + (u2 + u3);
            }

            // two interleaved compaction reduces (4 vals -> lanes 0..3)
            #pragma unroll
            for (int i = 0; i < 2; ++i) {
                float sa = (lane & 1) ? va[i] : va[i + 2];
                float sb = (lane & 1) ? vb[i] : vb[i + 2];
                float ca = __shfl_xor(sa, 1, 64);
                float cb = __shfl_xor(sb, 1, 64);
                va[i] = ((lane & 1) ? va[i + 2] : va[i]) + ca;
                vb[i] = ((lane & 1) ? vb[i + 2] : vb[i]) + cb;
            }
            {
                float sa = (lane & 2) ? va[0] : va[1];
                float sb = (lane & 2) ? vb[0] : vb[1];
                float ca = __shfl_xor(sa, 2, 64);
                float cb = __shfl_xor(sb, 2, 64);
                va[0] = ((lane & 2) ? va[1] : va[0]) + ca;
                vb[0] = ((lane & 2) ? vb[1] : vb[0]) + cb;
            }
            va[0] += __shfl_xor(va[0], 4, 64);
            vb[0] += __shfl_xor(vb[0], 4, 64);
            va[0] += __shfl_xor(va[0], 8, 64);
            vb[0] += __shfl_xor(vb[0], 8, 64);
            va[0] += __shfl_xor(va[0], 16, 64);
            vb[0] += __shfl_xor(vb[0], 16, 64);
            va[0] += __shfl_xor(va[0], 32, 64);
            vb[0] += __shfl_xor(vb[0], 32, 64);

            if (lane < 4) {
                int eg = ebase + g;
                if (eg < e1) out[(size_t)bout * E + eg] = MARGIN_F - va[0];
                if (eg + 1 < e1) out[(size_t)bout * E + eg + 1] = MARGIN_F - vb[0];
            }
        }

        __syncthreads();  // all waves done reading buf
        if (more) {
            #pragma unroll
            for (int p = 0; p < 4; ++p) buf[p * 256 + t] = sr[p];
        }
        __syncthreads();  // staged writes visible
    }
}

extern "C" void kernel_launch(void* const* d_in, const int* in_sizes, int n_in,
                              void* d_out, int out_size, void* d_ws,
                              size_t ws_size, hipStream_t stream) {
    const float* qh   = (const float*)d_in[0];  // (16,64,768)
    const float* W    = (const float*)d_in[1];  // (18,768)
    const float* brel = (const float*)d_in[2];  // (18,)
    const float* rel  = (const float*)d_in[3];  // (18,256)
    const float* ent  = (const float*)d_in[4];  // (E,512)
    const int*   hid  = (const int*)d_in[5];    // (16,)
    float* out = (float*)d_out;

    int E = in_sizes[4] / 512;

    float* rot = (float*)d_ws;  // 2*16*256 floats = 32 KB

    k_prep<<<dim3(16), 1024, 0, stream>>>(qh, W, brel, rel, ent, hid, rot);

    const int NB = 2048;            // chunk ~22 -> 3 phases of 8
    int chunk = (E + NB - 1) / NB;
    k_dist<<<dim3(NB), 256, 0, stream>>>(ent, rot, out, E, chunk);
}

// Round 14
// 65.809 us; speedup vs baseline: 1.1103x; 1.1103x over previous
//
#include <hip/hip_runtime.h>
#include <hip/hip_bf16.h>
#include <math.h>

#define MARGIN_F 6.0f
// phase = pr / (REL_RANGE/PI) = pr * (PI / 0.03125)
#define PHASE_SCALE 100.53096491487338f

// ---------------------------------------------------------------------------
// K1: fused prep. grid = 16 blocks (one per b), 1024 threads (16 waves).
// rot layout in ws: rot_re[16][256] at float offset 0, rot_im at 4096.
// ---------------------------------------------------------------------------
__global__ void k_prep(const float* __restrict__ qh, const float* __restrict__ W,
                       const float* __restrict__ brel,
                       const float* __restrict__ rel,
                       const float* __restrict__ ent, const int* __restrict__ hid,
                       float* __restrict__ rot) {
    __shared__ float q[768];
    __shared__ float sig[18];
    int b = blockIdx.x;
    int t = threadIdx.x;

    if (t < 768) {
        float s = 0.f;
        const float* base = qh + (size_t)b * 64 * 768 + t;
        #pragma unroll 8
        for (int srow = 0; srow < 64; ++srow) s += base[(size_t)srow * 768];
        q[t] = s * (1.0f / 64.0f);
    }
    __syncthreads();

    int wave = t >> 6, lane = t & 63;
    for (int r = wave; r < 18; r += 16) {
        float p = 0.f;
        for (int h = lane; h < 768; h += 64) p += q[h] * W[r * 768 + h];
        for (int off = 32; off; off >>= 1) p += __shfl_xor(p, off, 64);
        if (lane == 0) sig[r] = 1.0f / (1.0f + expf(-(p + brel[r])));
    }
    __syncthreads();

    if (t < 256) {
        int d = t;
        float pr = 0.f;
        #pragma unroll
        for (int r = 0; r < 18; ++r) pr += sig[r] * rel[r * 256 + d];
        float phase = pr * PHASE_SCALE;
        float sn, cs;
        sincosf(phase, &sn, &cs);
        int h0 = hid[b];
        float reh = ent[(size_t)h0 * 512 + d];
        float imh = ent[(size_t)h0 * 512 + 256 + d];
        rot[b * 256 + d]        = reh * cs - imh * sn;  // rot_re
        rot[4096 + b * 256 + d] = reh * sn + imh * cs;  // rot_im
    }
}

// ---------------------------------------------------------------------------
// K2: r10 compute core (4 waves/block, wave w owns b=4w..4w+3, pinned rot,
// G=2 interleaved compaction reduce) + REGISTER-FREE LDS staging via
// __builtin_amdgcn_global_load_lds (width 16): nothing for the allocator to
// spill (r13's sr[4] staging spilled 93 MB to scratch). Double-buffered
// 2x16 KB; next phase's DMA issues BEFORE compute; the single __syncthreads
// per phase drains vmcnt. Entity-row global traffic per block: 2 KB/entity
// (was 8 KB), served to all 4 waves from LDS.
// ---------------------------------------------------------------------------
#define PH 8  // entities per staging phase

__global__ __launch_bounds__(256, 4) void k_dist(const float* __restrict__ ent,
                                                 const float* __restrict__ rot,
                                                 float* __restrict__ out, int E,
                                                 int chunk) {
    __shared__ float4 buf[2][PH * 128];  // 2 x 16 KB

    int t = threadIdx.x;
    int lane = t & 63;
    int w4 = t >> 6;  // which 4 b's this wave owns

    const float4* rre4 = (const float4*)rot + (size_t)w4 * 4 * 64;
    const float4* rim4 = (const float4*)(rot + 4096) + (size_t)w4 * 4 * 64;
    float4 ra[4], ia[4];
    #pragma unroll
    for (int b = 0; b < 4; ++b) {
        ra[b] = rre4[b * 64 + lane];
        ia[b] = rim4[b * 64 + lane];
    }
    #pragma unroll
    for (int b = 0; b < 4; ++b) {
        asm volatile("" : "+v"(ra[b].x), "+v"(ra[b].y), "+v"(ra[b].z), "+v"(ra[b].w));
        asm volatile("" : "+v"(ia[b].x), "+v"(ia[b].y), "+v"(ia[b].z), "+v"(ia[b].w));
    }

    // b owned by lane l (<4) after compaction: b = 2*l0 + l1 (r8/r10 mapping)
    int bout = w4 * 4 + (((lane & 1) << 1) | ((lane >> 1) & 1));

    int e0 = blockIdx.x * chunk;
    if (e0 >= E) return;
    int e1 = min(e0 + chunk, E);
    int nph = (e1 - e0 + PH - 1) / PH;

    // Stage PH entity rows into buf[bi] starting at entity ebase.
    // Per wave: 4 global_load_lds (64 lanes x 16B each). LDS dest is the
    // wave-uniform base (HW adds lane*16); global src is per-lane, coalesced
    // 1KB; row index is wave-uniform per instruction.
    #define STAGE(bi, ebase)                                                     \
        {                                                                        \
            _Pragma("unroll") for (int p = 0; p < 4; ++p) {                      \
                int slotbase = p * 256 + w4 * 64;                                \
                int row = slotbase >> 7;                                         \
                int jbase = slotbase & 127;                                      \
                int er = min((ebase) + row, E - 1);                              \
                const float* src =                                               \
                    ent + (size_t)er * 512 + (size_t)(jbase + lane) * 4;         \
                __builtin_amdgcn_global_load_lds(                                \
                    (const __attribute__((address_space(1))) void*)src,          \
                    (__attribute__((address_space(3))) void*)&buf[bi][slotbase], \
                    16, 0, 0);                                                   \
            }                                                                    \
        }

    STAGE(0, e0);
    __syncthreads();  // drains vmcnt before first read

    int cur = 0;
    for (int ph = 0; ph < nph; ++ph) {
        int ebase = e0 + ph * PH;
        if (ph + 1 < nph) STAGE(cur ^ 1, ebase + PH);  // DMA in flight

        const float4* B = buf[cur];
        #pragma unroll
        for (int g = 0; g < PH; g += 2) {
            float4 tea = B[g * 128 + lane];
            float4 tia = B[g * 128 + 64 + lane];
            float4 teb = B[(g + 1) * 128 + lane];
            float4 tib = B[(g + 1) * 128 + 64 + lane];

            float va[4], vb[4];
            #pragma unroll
            for (int b = 0; b < 4; ++b) {
                float dx0 = ra[b].x - tea.x, dy0 = ia[b].x - tia.x;
                float dx1 = ra[b].y - tea.y, dy1 = ia[b].y - tia.y;
                float dx2 = ra[b].z - tea.z, dy2 = ia[b].z - tia.z;
                float dx3 = ra[b].w - tea.w, dy3 = ia[b].w - tia.w;
                float s0 = __builtin_amdgcn_sqrtf(dx0 * dx0 + dy0 * dy0);
                float s1 = __builtin_amdgcn_sqrtf(dx1 * dx1 + dy1 * dy1);
                float s2 = __builtin_amdgcn_sqrtf(dx2 * dx2 + dy2 * dy2);
                float s3 = __builtin_amdgcn_sqrtf(dx3 * dx3 + dy3 * dy3);
                va[b] = (s0 + s1) + (s2 + s3);

                float ex0 = ra[b].x - teb.x, ey0 = ia[b].x - tib.x;
                float ex1 = ra[b].y - teb.y, ey1 = ia[b].y - tib.y;
                float ex2 = ra[b].z - teb.z, ey2 = ia[b].z - tib.z;
                float ex3 = ra[b].w - teb.w, ey3 = ia[b].w - tib.w;
                float u0 = __builtin_amdgcn_sqrtf(ex0 * ex0 + ey0 * ey0);
                float u1 = __builtin_amdgcn_sqrtf(ex1 * ex1 + ey1 * ey1);
                float u2 = __builtin_amdgcn_sqrtf(ex2 * ex2 + ey2 * ey2);
                float u3 = __builtin_amdgcn_sqrtf(ex3 * ex3 + ey3 * ey3);
                vb[b] = (u0 + u1) + (u2 + u3);
            }

            // two interleaved compaction reduces (4 vals -> lanes 0..3)
            #pragma unroll
            for (int i = 0; i < 2; ++i) {
                float sa = (lane & 1) ? va[i] : va[i + 2];
                float sb = (lane & 1) ? vb[i] : vb[i + 2];
                float ca = __shfl_xor(sa, 1, 64);
                float cb = __shfl_xor(sb, 1, 64);
                va[i] = ((lane & 1) ? va[i + 2] : va[i]) + ca;
                vb[i] = ((lane & 1) ? vb[i + 2] : vb[i]) + cb;
            }
            {
                float sa = (lane & 2) ? va[0] : va[1];
                float sb = (lane & 2) ? vb[0] : vb[1];
                float ca = __shfl_xor(sa, 2, 64);
                float cb = __shfl_xor(sb, 2, 64);
                va[0] = ((lane & 2) ? va[1] : va[0]) + ca;
                vb[0] = ((lane & 2) ? vb[1] : vb[0]) + cb;
            }
            va[0] += __shfl_xor(va[0], 4, 64);
            vb[0] += __shfl_xor(vb[0], 4, 64);
            va[0] += __shfl_xor(va[0], 8, 64);
            vb[0] += __shfl_xor(vb[0], 8, 64);
            va[0] += __shfl_xor(va[0], 16, 64);
            vb[0] += __shfl_xor(vb[0], 16, 64);
            va[0] += __shfl_xor(va[0], 32, 64);
            vb[0] += __shfl_xor(vb[0], 32, 64);

            if (lane < 4) {
                int eg = ebase + g;
                if (eg < e1) out[(size_t)bout * E + eg] = MARGIN_F - va[0];
                if (eg + 1 < e1) out[(size_t)bout * E + eg + 1] = MARGIN_F - vb[0];
            }
        }

        __syncthreads();  // readers done + staged DMA drained (vmcnt before barrier)
        cur ^= 1;
    }
}

extern "C" void kernel_launch(void* const* d_in, const int* in_sizes, int n_in,
                              void* d_out, int out_size, void* d_ws,
                              size_t ws_size, hipStream_t stream) {
    const float* qh   = (const float*)d_in[0];  // (16,64,768)
    const float* W    = (const float*)d_in[1];  // (18,768)
    const float* brel = (const float*)d_in[2];  // (18,)
    const float* rel  = (const float*)d_in[3];  // (18,256)
    const float* ent  = (const float*)d_in[4];  // (E,512)
    const int*   hid  = (const int*)d_in[5];    // (16,)
    float* out = (float*)d_out;

    int E = in_sizes[4] / 512;

    float* rot = (float*)d_ws;  // 2*16*256 floats = 32 KB

    k_prep<<<dim3(16), 1024, 0, stream>>>(qh, W, brel, rel, ent, hid, rot);

    const int NB = 2048;            // chunk ~22 -> 3 phases of 8
    int chunk = (E + NB - 1) / NB;
    k_dist<<<dim3(NB), 256, 0, stream>>>(ent, rot, out, E, chunk);
}

// Round 15
// 60.433 us; speedup vs baseline: 1.2090x; 1.0890x over previous
//
#include <hip/hip_runtime.h>
#include <hip/hip_bf16.h>
#include <math.h>

#define MARGIN_F 6.0f
// phase = pr / (REL_RANGE/PI) = pr * (PI / 0.03125)
#define PHASE_SCALE 100.53096491487338f

// ---------------------------------------------------------------------------
// K1: fused prep. grid = 16 blocks (one per b), 1024 threads (16 waves).
// rot layout in ws: rot_re[16][256] at float offset 0, rot_im at 4096.
// ---------------------------------------------------------------------------
__global__ void k_prep(const float* __restrict__ qh, const float* __restrict__ W,
                       const float* __restrict__ brel,
                       const float* __restrict__ rel,
                       const float* __restrict__ ent, const int* __restrict__ hid,
                       float* __restrict__ rot) {
    __shared__ float q[768];
    __shared__ float sig[18];
    int b = blockIdx.x;
    int t = threadIdx.x;

    if (t < 768) {
        float s = 0.f;
        const float* base = qh + (size_t)b * 64 * 768 + t;
        #pragma unroll 8
        for (int srow = 0; srow < 64; ++srow) s += base[(size_t)srow * 768];
        q[t] = s * (1.0f / 64.0f);
    }
    __syncthreads();

    int wave = t >> 6, lane = t & 63;
    for (int r = wave; r < 18; r += 16) {
        float p = 0.f;
        for (int h = lane; h < 768; h += 64) p += q[h] * W[r * 768 + h];
        for (int off = 32; off; off >>= 1) p += __shfl_xor(p, off, 64);
        if (lane == 0) sig[r] = 1.0f / (1.0f + expf(-(p + brel[r])));
    }
    __syncthreads();

    if (t < 256) {
        int d = t;
        float pr = 0.f;
        #pragma unroll
        for (int r = 0; r < 18; ++r) pr += sig[r] * rel[r * 256 + d];
        float phase = pr * PHASE_SCALE;
        float sn, cs;
        sincosf(phase, &sn, &cs);
        int h0 = hid[b];
        float reh = ent[(size_t)h0 * 512 + d];
        float imh = ent[(size_t)h0 * 512 + 256 + d];
        rot[b * 256 + d]        = reh * cs - imh * sn;  // rot_re
        rot[4096 + b * 256 + d] = reh * sn + imh * cs;  // rot_im
    }
}

// ---------------------------------------------------------------------------
// K2: r10 core (4 waves/block, wave w owns b=4w..4w+3, pinned rot) with
// G=4 entities per iteration and a JOINT 16-value compaction reduce:
// 17 shuffles per 4 entities (vs r10's 14 per 2) and a 6-deep serial DS
// chain per 4 entities (vs 7 per 2) -> reduce slots -40%, serial DS latency
// per entity /2.3. After the 4 compaction steps, lane l<16 holds value
// idx=(l0<<3)|(l1<<2)|(l2<<1)|l3 with v[e*4+b]: e=(l0<<1)|l1, b=(l2<<1)|l3.
// te/ti demotion to L1 reloads (if any) is proven perf-neutral (r8 vs r10).
// ---------------------------------------------------------------------------
__global__ __launch_bounds__(256, 4) void k_dist(const float* __restrict__ ent,
                                                 const float* __restrict__ rot,
                                                 float* __restrict__ out, int E,
                                                 int chunk) {
    int lane = threadIdx.x & 63;
    int w4 = threadIdx.x >> 6;  // which 4 b's this wave owns

    const float4* rre4 = (const float4*)rot + (size_t)w4 * 4 * 64;
    const float4* rim4 = (const float4*)(rot + 4096) + (size_t)w4 * 4 * 64;
    float4 ra[4], ia[4];
    #pragma unroll
    for (int b = 0; b < 4; ++b) {
        ra[b] = rre4[b * 64 + lane];
        ia[b] = rim4[b * 64 + lane];
    }
    #pragma unroll
    for (int b = 0; b < 4; ++b) {
        asm volatile("" : "+v"(ra[b].x), "+v"(ra[b].y), "+v"(ra[b].z), "+v"(ra[b].w));
        asm volatile("" : "+v"(ia[b].x), "+v"(ia[b].y), "+v"(ia[b].z), "+v"(ia[b].w));
    }

    // store mapping after joint-16 compaction (lane < 16)
    int eoff = (((lane & 1) << 1) | ((lane >> 1) & 1));
    int bout = w4 * 4 + ((((lane >> 2) & 1) << 1) | ((lane >> 3) & 1));

    int e0 = blockIdx.x * chunk;
    if (e0 >= E) return;
    int e1 = min(e0 + chunk, E);

    for (int e = e0; e < e1; e += 4) {
        float4 te[4], ti[4];
        #pragma unroll
        for (int g = 0; g < 4; ++g) {
            int ee = min(e + g, e1 - 1);  // clamp tail reads (stores guarded)
            const float4* r4 = (const float4*)(ent + (size_t)ee * 512);
            te[g] = r4[lane];
            ti[g] = r4[64 + lane];
        }

        float v[16];  // v[g*4+b]
        #pragma unroll
        for (int g = 0; g < 4; ++g) {
            #pragma unroll
            for (int b = 0; b < 4; ++b) {
                float dx0 = ra[b].x - te[g].x, dy0 = ia[b].x - ti[g].x;
                float dx1 = ra[b].y - te[g].y, dy1 = ia[b].y - ti[g].y;
                float dx2 = ra[b].z - te[g].z, dy2 = ia[b].z - ti[g].z;
                float dx3 = ra[b].w - te[g].w, dy3 = ia[b].w - ti[g].w;
                float s0 = __builtin_amdgcn_sqrtf(dx0 * dx0 + dy0 * dy0);
                float s1 = __builtin_amdgcn_sqrtf(dx1 * dx1 + dy1 * dy1);
                float s2 = __builtin_amdgcn_sqrtf(dx2 * dx2 + dy2 * dy2);
                float s3 = __builtin_amdgcn_sqrtf(dx3 * dx3 + dy3 * dy3);
                v[g * 4 + b] = (s0 + s1) + (s2 + s3);
            }
        }

        // joint compaction: 16 values x 64 lanes -> 1 value on lanes 0..15
        #pragma unroll
        for (int i = 0; i < 8; ++i) {  // xor 1: idx bit3 <- lane bit0
            float s = (lane & 1) ? v[i] : v[i + 8];
            float c = __shfl_xor(s, 1, 64);
            v[i] = ((lane & 1) ? v[i + 8] : v[i]) + c;
        }
        #pragma unroll
        for (int i = 0; i < 4; ++i) {  // xor 2: idx bit2 <- lane bit1
            float s = (lane & 2) ? v[i] : v[i + 4];
            float c = __shfl_xor(s, 2, 64);
            v[i] = ((lane & 2) ? v[i + 4] : v[i]) + c;
        }
        #pragma unroll
        for (int i = 0; i < 2; ++i) {  // xor 4: idx bit1 <- lane bit2
            float s = (lane & 4) ? v[i] : v[i + 2];
            float c = __shfl_xor(s, 4, 64);
            v[i] = ((lane & 4) ? v[i + 2] : v[i]) + c;
        }
        {  // xor 8: idx bit0 <- lane bit3
            float s = (lane & 8) ? v[0] : v[1];
            float c = __shfl_xor(s, 8, 64);
            v[0] = ((lane & 8) ? v[1] : v[0]) + c;
        }
        v[0] += __shfl_xor(v[0], 16, 64);
        v[0] += __shfl_xor(v[0], 32, 64);

        if (lane < 16 && e + eoff < e1)
            out[(size_t)bout * E + e + eoff] = MARGIN_F - v[0];
    }
}

extern "C" void kernel_launch(void* const* d_in, const int* in_sizes, int n_in,
                              void* d_out, int out_size, void* d_ws,
                              size_t ws_size, hipStream_t stream) {
    const float* qh   = (const float*)d_in[0];  // (16,64,768)
    const float* W    = (const float*)d_in[1];  // (18,768)
    const float* brel = (const float*)d_in[2];  // (18,)
    const float* rel  = (const float*)d_in[3];  // (18,256)
    const float* ent  = (const float*)d_in[4];  // (E,512)
    const int*   hid  = (const int*)d_in[5];    // (16,)
    float* out = (float*)d_out;

    int E = in_sizes[4] / 512;

    float* rot = (float*)d_ws;  // 2*16*256 floats = 32 KB

    k_prep<<<dim3(16), 1024, 0, stream>>>(qh, W, brel, rel, ent, hid, rot);

    const int NB = 2048;            // 8192 waves
    int chunk = (E + NB - 1) / NB;  // ~22 consecutive entities per block
    k_dist<<<dim3(NB), 256, 0, stream>>>(ent, rot, out, E, chunk);
}

// Round 16
// 59.235 us; speedup vs baseline: 1.2335x; 1.0202x over previous
//
#include <hip/hip_runtime.h>
#include <hip/hip_bf16.h>
#include <math.h>

#define MARGIN_F 6.0f
// phase = pr / (REL_RANGE/PI) = pr * (PI / 0.03125)
#define PHASE_SCALE 100.53096491487338f

// ---------------------------------------------------------------------------
// K1: fused prep. grid = 16 blocks (one per b), 1024 threads (16 waves).
// rot layout in ws: rot_re[16][256] at float offset 0, rot_im at 4096.
// ---------------------------------------------------------------------------
__global__ void k_prep(const float* __restrict__ qh, const float* __restrict__ W,
                       const float* __restrict__ brel,
                       const float* __restrict__ rel,
                       const float* __restrict__ ent, const int* __restrict__ hid,
                       float* __restrict__ rot) {
    __shared__ float q[768];
    __shared__ float sig[18];
    int b = blockIdx.x;
    int t = threadIdx.x;

    if (t < 768) {
        float s = 0.f;
        const float* base = qh + (size_t)b * 64 * 768 + t;
        #pragma unroll 8
        for (int srow = 0; srow < 64; ++srow) s += base[(size_t)srow * 768];
        q[t] = s * (1.0f / 64.0f);
    }
    __syncthreads();

    int wave = t >> 6, lane = t & 63;
    for (int r = wave; r < 18; r += 16) {
        float p = 0.f;
        for (int h = lane; h < 768; h += 64) p += q[h] * W[r * 768 + h];
        for (int off = 32; off; off >>= 1) p += __shfl_xor(p, off, 64);
        if (lane == 0) sig[r] = 1.0f / (1.0f + expf(-(p + brel[r])));
    }
    __syncthreads();

    if (t < 256) {
        int d = t;
        float pr = 0.f;
        #pragma unroll
        for (int r = 0; r < 18; ++r) pr += sig[r] * rel[r * 256 + d];
        float phase = pr * PHASE_SCALE;
        float sn, cs;
        sincosf(phase, &sn, &cs);
        int h0 = hid[b];
        float reh = ent[(size_t)h0 * 512 + d];
        float imh = ent[(size_t)h0 * 512 + 256 + d];
        rot[b * 256 + d]        = reh * cs - imh * sn;  // rot_re
        rot[4096 + b * 256 + d] = reh * sn + imh * cs;  // rot_im
    }
}

// ---------------------------------------------------------------------------
// K2: r15 core (4 waves/block, wave w owns b=4w..4w+3, pinned rot, G=4,
// joint-16 compaction) + SOFTWARE-PIPELINED REDUCE: group i's 6-deep serial
// shuffle chain (~720cyc of ds_bpermute latency) executes interleaved with
// group i+1's independent ~1200cyc math block. Static double-buffer vA/vB,
// manually 2x-unrolled steady-state loop (no runtime indexing -> registers).
// r15 measured: busy 36.5us (instruction-bound, invariant across 7 shapes),
// idle 15.5us ~= the exposed DS chain. This hides it.
// ---------------------------------------------------------------------------
__global__ __launch_bounds__(256, 4) void k_dist(const float* __restrict__ ent,
                                                 const float* __restrict__ rot,
                                                 float* __restrict__ out, int E,
                                                 int chunk) {
    int lane = threadIdx.x & 63;
    int w4 = threadIdx.x >> 6;  // which 4 b's this wave owns

    const float4* rre4 = (const float4*)rot + (size_t)w4 * 4 * 64;
    const float4* rim4 = (const float4*)(rot + 4096) + (size_t)w4 * 4 * 64;
    float4 ra[4], ia[4];
    #pragma unroll
    for (int b = 0; b < 4; ++b) {
        ra[b] = rre4[b * 64 + lane];
        ia[b] = rim4[b * 64 + lane];
    }
    #pragma unroll
    for (int b = 0; b < 4; ++b) {
        asm volatile("" : "+v"(ra[b].x), "+v"(ra[b].y), "+v"(ra[b].z), "+v"(ra[b].w));
        asm volatile("" : "+v"(ia[b].x), "+v"(ia[b].y), "+v"(ia[b].z), "+v"(ia[b].w));
    }

    // store mapping after joint-16 compaction (lane < 16), proven in r15
    int eoff = (((lane & 1) << 1) | ((lane >> 1) & 1));
    int bout = w4 * 4 + ((((lane >> 2) & 1) << 1) | ((lane >> 3) & 1));

    int e0 = blockIdx.x * chunk;
    if (e0 >= E) return;
    int e1 = min(e0 + chunk, E);

// compute distances for 4 entities starting at EB into V[16] (V[g*4+b])
#define COMPUTE(V, EB)                                                        \
    {                                                                         \
        _Pragma("unroll") for (int g_ = 0; g_ < 4; ++g_) {                    \
            int ee_ = min((EB) + g_, e1 - 1);                                 \
            const float4* r4_ = (const float4*)(ent + (size_t)ee_ * 512);     \
            float4 te_ = r4_[lane];                                           \
            float4 ti_ = r4_[64 + lane];                                      \
            _Pragma("unroll") for (int b_ = 0; b_ < 4; ++b_) {                \
                float dx0 = ra[b_].x - te_.x, dy0 = ia[b_].x - ti_.x;         \
                float dx1 = ra[b_].y - te_.y, dy1 = ia[b_].y - ti_.y;         \
                float dx2 = ra[b_].z - te_.z, dy2 = ia[b_].z - ti_.z;         \
                float dx3 = ra[b_].w - te_.w, dy3 = ia[b_].w - ti_.w;         \
                float s0 = __builtin_amdgcn_sqrtf(dx0 * dx0 + dy0 * dy0);     \
                float s1 = __builtin_amdgcn_sqrtf(dx1 * dx1 + dy1 * dy1);     \
                float s2 = __builtin_amdgcn_sqrtf(dx2 * dx2 + dy2 * dy2);     \
                float s3 = __builtin_amdgcn_sqrtf(dx3 * dx3 + dy3 * dy3);     \
                V[g_ * 4 + b_] = (s0 + s1) + (s2 + s3);                       \
            }                                                                 \
        }                                                                     \
    }

// joint compaction of V[16] -> lanes 0..15, then guarded store for group EB
#define RSTORE(V, EB)                                                         \
    {                                                                         \
        _Pragma("unroll") for (int i_ = 0; i_ < 8; ++i_) {                    \
            float s_ = (lane & 1) ? V[i_] : V[i_ + 8];                        \
            float c_ = __shfl_xor(s_, 1, 64);                                 \
            V[i_] = ((lane & 1) ? V[i_ + 8] : V[i_]) + c_;                    \
        }                                                                     \
        _Pragma("unroll") for (int i_ = 0; i_ < 4; ++i_) {                    \
            float s_ = (lane & 2) ? V[i_] : V[i_ + 4];                        \
            float c_ = __shfl_xor(s_, 2, 64);                                 \
            V[i_] = ((lane & 2) ? V[i_ + 4] : V[i_]) + c_;                    \
        }                                                                     \
        _Pragma("unroll") for (int i_ = 0; i_ < 2; ++i_) {                    \
            float s_ = (lane & 4) ? V[i_] : V[i_ + 2];                        \
            float c_ = __shfl_xor(s_, 4, 64);                                 \
            V[i_] = ((lane & 4) ? V[i_ + 2] : V[i_]) + c_;                    \
        }                                                                     \
        {                                                                     \
            float s_ = (lane & 8) ? V[0] : V[1];                              \
            float c_ = __shfl_xor(s_, 8, 64);                                 \
            V[0] = ((lane & 8) ? V[1] : V[0]) + c_;                           \
        }                                                                     \
        V[0] += __shfl_xor(V[0], 16, 64);                                     \
        V[0] += __shfl_xor(V[0], 32, 64);                                     \
        if (lane < 16 && (EB) + eoff < e1)                                    \
            out[(size_t)bout * E + (EB) + eoff] = MARGIN_F - V[0];            \
    }

    int ngroups = (e1 - e0 + 3) >> 2;
    float vA[16], vB[16];

    COMPUTE(vA, e0);  // prologue: group 0
    int g = 1;
    for (; g + 1 < ngroups; g += 2) {
        // COMPUTE(vB) and RSTORE(vA) are independent: scheduler interleaves
        COMPUTE(vB, e0 + g * 4);
        RSTORE(vA, e0 + (g - 1) * 4);
        COMPUTE(vA, e0 + (g + 1) * 4);
        RSTORE(vB, e0 + g * 4);
    }
    if (g < ngroups) {  // one trailing group (even ngroups)
        COMPUTE(vB, e0 + g * 4);
        RSTORE(vA, e0 + (g - 1) * 4);
        RSTORE(vB, e0 + g * 4);
    } else {  // odd ngroups: vA holds the last group
        RSTORE(vA, e0 + (ngroups - 1) * 4);
    }

#undef COMPUTE
#undef RSTORE
}

extern "C" void kernel_launch(void* const* d_in, const int* in_sizes, int n_in,
                              void* d_out, int out_size, void* d_ws,
                              size_t ws_size, hipStream_t stream) {
    const float* qh   = (const float*)d_in[0];  // (16,64,768)
    const float* W    = (const float*)d_in[1];  // (18,768)
    const float* brel = (const float*)d_in[2];  // (18,)
    const float* rel  = (const float*)d_in[3];  // (18,256)
    const float* ent  = (const float*)d_in[4];  // (E,512)
    const int*   hid  = (const int*)d_in[5];    // (16,)
    float* out = (float*)d_out;

    int E = in_sizes[4] / 512;

    float* rot = (float*)d_ws;  // 2*16*256 floats = 32 KB

    k_prep<<<dim3(16), 1024, 0, stream>>>(qh, W, brel, rel, ent, hid, rot);

    const int NB = 2048;            // 8192 waves
    int chunk = (E + NB - 1) / NB;  // ~22 consecutive entities per block
    k_dist<<<dim3(NB), 256, 0, stream>>>(ent, rot, out, E, chunk);
}